// Round 2
// baseline (563.750 us; speedup 1.0000x reference)
//
#include <hip/hip_runtime.h>
#include <hip/hip_bf16.h>
#include <stdint.h>

// ConvNACCell: out[n,co,h,w] = sum_{ci,kh,kw} x[n,ci,h+kh-1,w+kw-1] * W[co,ci,kh,kw]
// W = tanh(W_hat)*sigmoid(M_hat). Implicit GEMM, mfma_f32_16x16x32_bf16, fp32 acc.
// Rolling 4-slot row-ring pipeline: stage row r+3 (issue-early/write-late) while
// computing output row r from staged rows {r-1, r, r+1} (local lr = r..r+2).

#define CH_IN  64
#define CH_OUT 128
#define HW     256

typedef __attribute__((ext_vector_type(8))) short short8;   // 8 bf16 = 4 VGPR
typedef __attribute__((ext_vector_type(4))) float f32x4;

// RNE fp32 -> bf16 pair packed into u32 (lo = a, hi = b). Inputs finite.
static __device__ __forceinline__ uint32_t pack_bf16(float a, float b) {
    uint32_t ua = __builtin_bit_cast(uint32_t, a);
    uint32_t ub = __builtin_bit_cast(uint32_t, b);
    ua = (ua + 0x7FFFu + ((ua >> 16) & 1u)) >> 16;
    ub = (ub + 0x7FFFu + ((ub >> 16) & 1u));
    return (ua & 0xFFFFu) | (ub & 0xFFFF0000u);
}

// ---------------------------------------------------------------------------
// Prep: W = tanh(W_hat)*sigmoid(M_hat) as bf16 A-fragments.
//   frag[t][ms][s][lane] (16B): elem j = A[co = ms*16 + (lane&15)]
//                                        [ci = s*32 + (lane>>4)*8 + j], tap t.
// Total 9*8*2*64*16 = 147,456 B in d_ws.
// ---------------------------------------------------------------------------
__global__ void __launch_bounds__(256) nac_prep(const float* __restrict__ Wh,
                                                const float* __restrict__ Mh,
                                                uint32_t* __restrict__ Af) {
    int f = blockIdx.x * 256 + threadIdx.x;   // 0..9215
    if (f >= 9 * 8 * 2 * 64) return;
    int lane = f & 63;
    int s    = (f >> 6) & 1;
    int ms   = (f >> 7) & 7;
    int t    = f >> 10;
    int co   = ms * 16 + (lane & 15);
    int ci0  = s * 32 + ((lane >> 4) << 3);

    uint32_t pk[4];
#pragma unroll
    for (int j2 = 0; j2 < 4; ++j2) {
        int ci = ci0 + 2 * j2;
        int k0 = ci * 9 + t;
        int k1 = k0 + 9;
        float w0 = tanhf(Wh[co * 576 + k0]);
        float m0 = Mh[co * 576 + k0];
        float w1 = tanhf(Wh[co * 576 + k1]);
        float m1 = Mh[co * 576 + k1];
        float v0 = w0 * (1.0f / (1.0f + expf(-m0)));
        float v1 = w1 * (1.0f / (1.0f + expf(-m1)));
        pk[j2] = pack_bf16(v0, v1);
    }
    int fragidx = ((t * 8 + ms) * 2 + s) * 64 + lane;
    reinterpret_cast<uint4*>(Af)[fragidx] = make_uint4(pk[0], pk[1], pk[2], pk[3]);
}

// ---------------------------------------------------------------------------
// Conv. Block = 128co x 16h x 64w. 1024 blocks (= 4/CU x 256 CU exactly).
// LDS ring: [pg(8)][slot(4)][c(0..65, stride CPAD=69)] of u32x4;
//   u32x4 at (pg,slot,c) = bf16 ci pair stream: elem j = ci pg*8+j, pixel c.
// ---------------------------------------------------------------------------
#define NSLOT 4
#define CW    66                    // staged columns: w0-1 .. w0+64
#define CPAD  69                    // padded row stride (u32x4 units) - bank stagger
#define SLOT_B (CPAD * 16)          // 1104 B
#define PG_B   (NSLOT * CPAD * 16)  // 4416 B
#define S_B    (4 * PG_B)           // 17664 B (k-step stride: pg += 4)

__global__ void __launch_bounds__(256, 4)
nac_conv(const float* __restrict__ x, const uint32_t* __restrict__ Af,
         float* __restrict__ out) {
    __shared__ uint32_t xl[8 * NSLOT * CPAD * 4];   // 35,328 B -> 4 blocks/CU

    // Bijective XCD-chunked swizzle: 1024 blocks, 128 per XCD chunk.
    unsigned bid = blockIdx.x;
    unsigned idx = (bid & 7u) * 128u + (bid >> 3);
    int ht = idx & 15;
    int wt = (idx >> 4) & 3;
    int n  = idx >> 6;
    int h0 = ht * 16;
    int w0 = wt * 64;

    int tid  = threadIdx.x;
    int lane = tid & 63;
    int wm   = tid >> 6;            // co quarter (32 co per wave)
    int col  = lane & 15;
    int row4 = lane >> 4;

    const float* xn = x + (size_t)n * CH_IN * HW * HW;

    // Stage tasks: main 512 = (pg,c<64) as taskA(tid)+taskB(tid+256);
    // tail 16 = (pg, c in {64,65}) on tid<16.
    int  pgA  = tid >> 6;           // 0..3 (taskB uses pgA+4)
    int  cA   = tid & 63;
    bool hasC = tid < 16;
    int  pgC  = tid >> 1;
    int  cC   = 64 + (tid & 1);
    bool wvA  = (unsigned)(w0 - 1 + cA) < (unsigned)HW;
    bool wvC  = (unsigned)(w0 - 1 + cC) < (unsigned)HW;

    auto issue = [&](int lr, float* xa, float* xb, float* xc) {
        int hrow = h0 - 1 + lr;
        bool rv = (unsigned)hrow < (unsigned)HW;
        bool vA = rv && wvA;
        bool vC = rv && wvC && hasC;
        const float* pA = xn + (size_t)hrow * HW + (w0 - 1 + cA);
        const float* pC = xn + (size_t)hrow * HW + (w0 - 1 + cC);
        if (vA) {
#pragma unroll
            for (int e = 0; e < 8; ++e) {
                xa[e] = pA[(size_t)(pgA * 8 + e) * HW * HW];
                xb[e] = pA[(size_t)((pgA + 4) * 8 + e) * HW * HW];
            }
        } else {
#pragma unroll
            for (int e = 0; e < 8; ++e) { xa[e] = 0.f; xb[e] = 0.f; }
        }
        if (vC) {
#pragma unroll
            for (int e = 0; e < 8; ++e) xc[e] = pC[(size_t)(pgC * 8 + e) * HW * HW];
        } else {
#pragma unroll
            for (int e = 0; e < 8; ++e) xc[e] = 0.f;
        }
    };

    auto commit = [&](int lr, const float* xa, const float* xb, const float* xc) {
        int slot = lr & 3;
        uint4 w;
        w.x = pack_bf16(xa[0], xa[1]); w.y = pack_bf16(xa[2], xa[3]);
        w.z = pack_bf16(xa[4], xa[5]); w.w = pack_bf16(xa[6], xa[7]);
        *reinterpret_cast<uint4*>(&xl[((pgA * NSLOT + slot) * CPAD + cA) * 4]) = w;
        w.x = pack_bf16(xb[0], xb[1]); w.y = pack_bf16(xb[2], xb[3]);
        w.z = pack_bf16(xb[4], xb[5]); w.w = pack_bf16(xb[6], xb[7]);
        *reinterpret_cast<uint4*>(&xl[(((pgA + 4) * NSLOT + slot) * CPAD + cA) * 4]) = w;
        if (hasC) {
            w.x = pack_bf16(xc[0], xc[1]); w.y = pack_bf16(xc[2], xc[3]);
            w.z = pack_bf16(xc[4], xc[5]); w.w = pack_bf16(xc[6], xc[7]);
            *reinterpret_cast<uint4*>(&xl[((pgC * NSLOT + slot) * CPAD + cC) * 4]) = w;
        }
    };

    // Prologue: stage local rows 0,1,2.
    {
        float xa[8], xb[8], xc[8];
#pragma unroll
        for (int lr = 0; lr < 3; ++lr) {
            issue(lr, xa, xb, xc);
            commit(lr, xa, xb, xc);
        }
    }
    __syncthreads();

    f32x4 acc[2][4];
#pragma unroll
    for (int mi = 0; mi < 2; ++mi)
#pragma unroll
        for (int ni = 0; ni < 4; ++ni) acc[mi][ni] = (f32x4){0.f, 0.f, 0.f, 0.f};

    const short8* Afr = reinterpret_cast<const short8*>(Af);
    const char* ldsb = reinterpret_cast<const char*>(xl);
    const int thrbase = row4 * PG_B + col * 16;

    for (int r = 0; r < 16; ++r) {
        float xa[8], xb[8], xc[8];
        const bool st = (r < 15);
        if (st) issue(r + 3, xa, xb, xc);     // issue-early: hides under MFMA

        int bk0 = thrbase + ((r + 0) & 3) * SLOT_B;
        int bk1 = thrbase + ((r + 1) & 3) * SLOT_B;
        int bk2 = thrbase + ((r + 2) & 3) * SLOT_B;

#pragma unroll
        for (int t = 0; t < 9; ++t) {
            const int kh = t / 3, kw = t % 3;
            const int bkh = (kh == 0) ? bk0 : ((kh == 1) ? bk1 : bk2);
#pragma unroll
            for (int s = 0; s < 2; ++s) {
                short8 a0 = Afr[((t * 8 + wm * 2 + 0) * 2 + s) * 64 + lane];
                short8 a1 = Afr[((t * 8 + wm * 2 + 1) * 2 + s) * 64 + lane];
#pragma unroll
                for (int ni = 0; ni < 4; ++ni) {
                    short8 b = *reinterpret_cast<const short8*>(
                        ldsb + bkh + s * S_B + (ni * 16 + kw) * 16);
                    acc[0][ni] = __builtin_amdgcn_mfma_f32_16x16x32_bf16(
                        a0, b, acc[0][ni], 0, 0, 0);
                    acc[1][ni] = __builtin_amdgcn_mfma_f32_16x16x32_bf16(
                        a1, b, acc[1][ni], 0, 0, 0);
                }
            }
        }

        if (st) {
            commit(r + 3, xa, xb, xc);        // write-late: loads already landed
            __syncthreads();
        }

        // Store output row h0+r (drains during next chunk's compute).
        size_t ob = (size_t)n * CH_OUT * HW * HW + (size_t)(h0 + r) * HW + w0;
#pragma unroll
        for (int mi = 0; mi < 2; ++mi)
#pragma unroll
            for (int reg = 0; reg < 4; ++reg) {
                int co = wm * 32 + mi * 16 + row4 * 4 + reg;
                float* op = out + ob + (size_t)co * HW * HW;
#pragma unroll
                for (int ni = 0; ni < 4; ++ni) op[ni * 16 + col] = acc[mi][ni][reg];
            }
#pragma unroll
        for (int mi = 0; mi < 2; ++mi)
#pragma unroll
            for (int ni = 0; ni < 4; ++ni) acc[mi][ni] = (f32x4){0.f, 0.f, 0.f, 0.f};
    }
}

extern "C" void kernel_launch(void* const* d_in, const int* in_sizes, int n_in,
                              void* d_out, int out_size, void* d_ws, size_t ws_size,
                              hipStream_t stream) {
    const float* x  = (const float*)d_in[0];
    const float* Wh = (const float*)d_in[1];
    const float* Mh = (const float*)d_in[2];
    float* out = (float*)d_out;
    uint32_t* Af = (uint32_t*)d_ws;   // 147,456 B of A fragments

    nac_prep<<<36, 256, 0, stream>>>(Wh, Mh, Af);
    nac_conv<<<1024, 256, 0, stream>>>(x, Af, out);
}

// Round 3
// 376.745 us; speedup vs baseline: 1.4964x; 1.4964x over previous
//
#include <hip/hip_runtime.h>
#include <hip/hip_bf16.h>
#include <stdint.h>

// ConvNACCell: out[n,co,h,w] = sum_{ci,kh,kw} x[n,ci,h+kh-1,w+kw-1] * W[co,ci,kh,kw]
// W = tanh(W_hat)*sigmoid(M_hat). Implicit GEMM, mfma_f32_16x16x32_bf16, fp32 acc.
// Pass 1: x fp32 NCHW -> bf16 NHWC in ws. Pass 2: conv with global_load_lds
// staging (linear LDS dest, per-lane XOR-swizzled global source) + swizzled
// ds_read_b128 B-fragments (conflict-free).

#define CH_IN  64
#define CH_OUT 128
#define HW     256

typedef __attribute__((ext_vector_type(8))) short short8;   // 8 bf16 = 4 VGPR
typedef __attribute__((ext_vector_type(4))) float f32x4;

// ws layout (bytes)
#define AF_BYTES 147456u                    // A fragments
#define ZP_BYTE  147456u                    // 256 B zero page
#define XB_BYTE  147712u                    // x bf16 NHWC, 134,217,728 B
#define WS_NEED  (147712ull + 134217728ull)

// RNE fp32 -> bf16 pair packed into u32 (lo = a, hi = b). Inputs finite.
static __device__ __forceinline__ uint32_t pack_bf16(float a, float b) {
    uint32_t ua = __builtin_bit_cast(uint32_t, a);
    uint32_t ub = __builtin_bit_cast(uint32_t, b);
    ua = (ua + 0x7FFFu + ((ua >> 16) & 1u)) >> 16;
    ub = (ub + 0x7FFFu + ((ub >> 16) & 1u));
    return (ua & 0xFFFFu) | (ub & 0xFFFF0000u);
}

// ---------------------------------------------------------------------------
// Prep: W = tanh(W_hat)*sigmoid(M_hat) as bf16 A-fragments + zero page.
//   frag[t][ms][s][lane] (16B): elem j = A[co = ms*16 + (lane&15)]
//                                        [ci = s*32 + (lane>>4)*8 + j], tap t.
// ---------------------------------------------------------------------------
__global__ void __launch_bounds__(256) nac_prep(const float* __restrict__ Wh,
                                                const float* __restrict__ Mh,
                                                uint32_t* __restrict__ ws32) {
    if (blockIdx.x == 0 && threadIdx.x < 64) ws32[ZP_BYTE / 4 + threadIdx.x] = 0;

    int f = blockIdx.x * 256 + threadIdx.x;   // 0..9215
    if (f >= 9 * 8 * 2 * 64) return;
    int lane = f & 63;
    int s    = (f >> 6) & 1;
    int ms   = (f >> 7) & 7;
    int t    = f >> 10;
    int co   = ms * 16 + (lane & 15);
    int ci0  = s * 32 + ((lane >> 4) << 3);

    uint32_t pk[4];
#pragma unroll
    for (int j2 = 0; j2 < 4; ++j2) {
        int ci = ci0 + 2 * j2;
        int k0 = ci * 9 + t;
        int k1 = k0 + 9;
        float w0 = tanhf(Wh[co * 576 + k0]);
        float m0 = Mh[co * 576 + k0];
        float w1 = tanhf(Wh[co * 576 + k1]);
        float m1 = Mh[co * 576 + k1];
        float v0 = w0 * (1.0f / (1.0f + expf(-m0)));
        float v1 = w1 * (1.0f / (1.0f + expf(-m1)));
        pk[j2] = pack_bf16(v0, v1);
    }
    int fragidx = ((t * 8 + ms) * 2 + s) * 64 + lane;
    reinterpret_cast<uint4*>(ws32)[fragidx] = make_uint4(pk[0], pk[1], pk[2], pk[3]);
}

// ---------------------------------------------------------------------------
// Convert: x [16,64,256,256] fp32 NCHW -> xb [16,256,256,64] bf16 NHWC.
// Block = (n,h). Thread = pixel w. All loads/stores coalesced per instruction.
// ---------------------------------------------------------------------------
__global__ void __launch_bounds__(256) nac_convert(const float* __restrict__ x,
                                                   uint32_t* __restrict__ xb) {
    int bid = blockIdx.x;            // 4096
    int h   = bid & 255;
    int n   = bid >> 8;
    int px  = threadIdx.x;
    const float* xr = x + ((size_t)n * CH_IN * HW + h) * HW + px;
    uint32_t* orow = xb + ((size_t)(n * HW + h) * HW + px) * 32;   // u32 units
#pragma unroll
    for (int g = 0; g < 8; ++g) {
        float v0 = xr[(size_t)(g * 8 + 0) * HW * HW];
        float v1 = xr[(size_t)(g * 8 + 1) * HW * HW];
        float v2 = xr[(size_t)(g * 8 + 2) * HW * HW];
        float v3 = xr[(size_t)(g * 8 + 3) * HW * HW];
        float v4 = xr[(size_t)(g * 8 + 4) * HW * HW];
        float v5 = xr[(size_t)(g * 8 + 5) * HW * HW];
        float v6 = xr[(size_t)(g * 8 + 6) * HW * HW];
        float v7 = xr[(size_t)(g * 8 + 7) * HW * HW];
        uint4 wd;
        wd.x = pack_bf16(v0, v1); wd.y = pack_bf16(v2, v3);
        wd.z = pack_bf16(v4, v5); wd.w = pack_bf16(v6, v7);
        *reinterpret_cast<uint4*>(orow + g * 4) = wd;
    }
}

// ---------------------------------------------------------------------------
// Conv. Block = 128co x 2h x 64w, grid 8192. LDS tile: 4 rows (h0-1..h0+2) x
// 66 px (w0-1..w0+64) x 8 granules of 16B (8 ci each). Granule idx =
// 8*(r*66+p)+g, byte = idx*16. Stage: global_load_lds, linear dest, per-lane
// source granule g^(p&7) (read-side applies same XOR -> conflict-free).
// ---------------------------------------------------------------------------
__global__ void __launch_bounds__(256)
nac_conv2(const uint32_t* __restrict__ xb, const uint32_t* __restrict__ Af,
          float* __restrict__ out, const uint32_t* __restrict__ zp) {
    __shared__ __align__(1024) uint32_t xl[2112 * 4];   // 33,792 B

    unsigned bid = blockIdx.x;
    unsigned idx = (bid & 7u) * 1024u + (bid >> 3);   // bijective XCD swizzle
    int ht = idx & 127;
    int wt = (idx >> 7) & 3;
    int n  = idx >> 9;
    int h0 = ht * 2;
    int w0 = wt * 64;

    int tid = threadIdx.x;
    int g   = tid & 7;
    int q   = tid >> 3;

    // ---- stage: 2112 granules = 8 full rounds + 64-granule tail (wave 0) ----
#pragma unroll
    for (int it = 0; it < 9; ++it) {
        if (it < 8 || tid < 64) {
            const int rp = it * 32 + q;                 // 0..263 = r*66+p
            const int r0 = (it * 32) / 66;              // compile-time
            const int r  = (rp >= (r0 + 1) * 66) ? r0 + 1 : r0;
            const int p  = rp - r * 66;
            const int hh = h0 - 1 + r;
            const int ww = w0 - 1 + p;
            const bool valid = ((unsigned)hh < 256u) & ((unsigned)ww < 256u);
            const uint32_t* src = valid
                ? xb + ((size_t)((n * 256 + hh) * 256 + ww) * 32 + ((g ^ (p & 7)) << 2))
                : zp;
            __builtin_amdgcn_global_load_lds(
                (const __attribute__((address_space(1))) uint32_t*)src,
                (__attribute__((address_space(3))) uint32_t*)&xl[(it * 256 + (tid & ~63)) * 4],
                16, 0, 0);
        }
    }
    __syncthreads();

    // ---- compute ----
    int lane = tid & 63;
    int wv   = tid >> 6;
    int wm   = wv >> 1;        // co half
    int wn   = wv & 1;         // output row within tile
    int col  = lane & 15;
    int row4 = lane >> 4;

    // per-thread B byte-offset pieces: pixel term + swizzled granule term
    int bcol[2][3];
#pragma unroll
    for (int s = 0; s < 2; ++s)
#pragma unroll
        for (int kw = 0; kw < 3; ++kw)
            bcol[s][kw] = (col + kw) * 128 +
                          ((((s * 4) + row4) ^ ((col + kw) & 7)) * 16);

    f32x4 acc[4][4];
#pragma unroll
    for (int mi = 0; mi < 4; ++mi)
#pragma unroll
        for (int ni = 0; ni < 4; ++ni) acc[mi][ni] = (f32x4){0.f, 0.f, 0.f, 0.f};

    const short8* Afr = reinterpret_cast<const short8*>(Af);
    const char* lb = reinterpret_cast<const char*>(xl);

#pragma unroll
    for (int t = 0; t < 9; ++t) {
        const int kh = t / 3, kw = t % 3;
        short8 a[2][4];
#pragma unroll
        for (int s = 0; s < 2; ++s)
#pragma unroll
            for (int mi = 0; mi < 4; ++mi)
                a[s][mi] = Afr[((t * 8 + (wm * 4 + mi)) * 2 + s) * 64 + lane];
#pragma unroll
        for (int s = 0; s < 2; ++s) {
#pragma unroll
            for (int ni = 0; ni < 4; ++ni) {
                short8 b = *reinterpret_cast<const short8*>(
                    lb + ((wn + kh) * 66 + ni * 16) * 128 + bcol[s][kw]);
#pragma unroll
                for (int mi = 0; mi < 4; ++mi)
                    acc[mi][ni] = __builtin_amdgcn_mfma_f32_16x16x32_bf16(
                        a[s][mi], b, acc[mi][ni], 0, 0, 0);
            }
        }
    }

    // ---- store (C/D: col = lane&15, row = (lane>>4)*4 + reg) ----
#pragma unroll
    for (int mi = 0; mi < 4; ++mi) {
#pragma unroll
        for (int reg = 0; reg < 4; ++reg) {
            int co = wm * 64 + mi * 16 + row4 * 4 + reg;
            float* op = out + (((size_t)n * CH_OUT + co) * HW + (h0 + wn)) * HW + w0;
#pragma unroll
            for (int ni = 0; ni < 4; ++ni) op[ni * 16 + col] = acc[mi][ni][reg];
        }
    }
}

// ---------------------------------------------------------------------------
// Fallback (round-1 proven kernel) if ws is too small for the bf16 buffer.
// ---------------------------------------------------------------------------
__global__ void __launch_bounds__(256) nac_conv_fb(const float* __restrict__ x,
                                                   const uint32_t* __restrict__ Af,
                                                   float* __restrict__ out) {
    __shared__ uint32_t xl[8 * 272 * 4];

    unsigned bid = blockIdx.x;
    unsigned idx = (bid & 7u) * 1024u + (bid >> 3);
    int ht = idx & 127;
    int wt = (idx >> 7) & 3;
    int n  = idx >> 9;
    int h0 = ht * 2;
    int w0 = wt * 64;
    int tid = threadIdx.x;

    const float* xn = x + (size_t)n * CH_IN * HW * HW;
    for (int it = 0; it < 9; ++it) {
        int task = tid + it * 256;
        if (task < 2176) {
            int r   = task / 544;
            int rem = task - r * 544;
            int pg  = rem / 68;
            int c   = rem - pg * 68;
            int hrow = h0 - 1 + r;
            int w    = w0 - 1 + c;
            float v[8];
            if ((unsigned)hrow < 256u && (unsigned)w < 256u) {
                const float* p = xn + ((size_t)(pg * 8) * HW + hrow) * HW + w;
#pragma unroll
                for (int e = 0; e < 8; ++e) v[e] = p[(size_t)e * HW * HW];
            } else {
#pragma unroll
                for (int e = 0; e < 8; ++e) v[e] = 0.0f;
            }
            uint4 wd;
            wd.x = pack_bf16(v[0], v[1]);
            wd.y = pack_bf16(v[2], v[3]);
            wd.z = pack_bf16(v[4], v[5]);
            wd.w = pack_bf16(v[6], v[7]);
            *reinterpret_cast<uint4*>(&xl[(pg * 272 + r * 68 + c) * 4]) = wd;
        }
    }
    __syncthreads();

    int lane = tid & 63;
    int wv   = tid >> 6;
    int wm   = wv >> 1;
    int wn   = wv & 1;
    int row4 = lane >> 4;
    int col  = lane & 15;

    f32x4 acc[4][4];
#pragma unroll
    for (int mi = 0; mi < 4; ++mi)
#pragma unroll
        for (int ni = 0; ni < 4; ++ni) acc[mi][ni] = (f32x4){0.f, 0.f, 0.f, 0.f};

    const short8* Afr = reinterpret_cast<const short8*>(Af);
    for (int t = 0; t < 9; ++t) {
        int kh = t / 3, kw = t % 3;
        short8 a[2][4];
#pragma unroll
        for (int s = 0; s < 2; ++s)
#pragma unroll
            for (int mi = 0; mi < 4; ++mi)
                a[s][mi] = Afr[((t * 8 + (wm * 4 + mi)) * 2 + s) * 64 + lane];
#pragma unroll
        for (int s = 0; s < 2; ++s) {
            short8 b[4];
#pragma unroll
            for (int ni = 0; ni < 4; ++ni) {
                int pg = s * 4 + row4;
                int pp = (wn + kh) * 68 + ni * 16 + col + kw;
                b[ni] = *reinterpret_cast<const short8*>(&xl[(pg * 272 + pp) * 4]);
            }
#pragma unroll
            for (int mi = 0; mi < 4; ++mi)
#pragma unroll
                for (int ni = 0; ni < 4; ++ni)
                    acc[mi][ni] = __builtin_amdgcn_mfma_f32_16x16x32_bf16(
                        a[s][mi], b[ni], acc[mi][ni], 0, 0, 0);
        }
    }

#pragma unroll
    for (int mi = 0; mi < 4; ++mi) {
#pragma unroll
        for (int reg = 0; reg < 4; ++reg) {
            int co = wm * 64 + mi * 16 + row4 * 4 + reg;
            float* op = out + (((size_t)n * CH_OUT + co) * HW + (h0 + wn)) * HW + w0;
#pragma unroll
            for (int ni = 0; ni < 4; ++ni) op[ni * 16 + col] = acc[mi][ni][reg];
        }
    }
}

extern "C" void kernel_launch(void* const* d_in, const int* in_sizes, int n_in,
                              void* d_out, int out_size, void* d_ws, size_t ws_size,
                              hipStream_t stream) {
    const float* x  = (const float*)d_in[0];
    const float* Wh = (const float*)d_in[1];
    const float* Mh = (const float*)d_in[2];
    float* out = (float*)d_out;
    uint32_t* ws32 = (uint32_t*)d_ws;
    const uint32_t* Af = ws32;
    const uint32_t* zp = ws32 + ZP_BYTE / 4;
    uint32_t* xb = ws32 + XB_BYTE / 4;

    nac_prep<<<36, 256, 0, stream>>>(Wh, Mh, ws32);
    if (ws_size >= WS_NEED) {
        nac_convert<<<4096, 256, 0, stream>>>(x, xb);
        nac_conv2<<<8192, 256, 0, stream>>>(xb, Af, out, zp);
    } else {
        nac_conv_fb<<<8192, 256, 0, stream>>>(x, Af, out);
    }
}